// Round 20
// baseline (66.309 us; speedup 1.0000x reference)
//
#include <hip/hip_runtime.h>

// DMV inside — linear-domain sum-product, paired spans, REGISTER HISTORY.
// One block per batch item, 512 threads = 64 groups of 8. Group g owns span
// (h=g, e=h+w) at every width: the right-side history F[h][h+*], I[h][h+*]
// is produced and consumed ONLY by group g -> kept in per-lane registers
// fS[8], iS[8] (slot j = element k = lg+8j; write slot w>>3 is compile-time
// per NJ case). Upper-triangle sI writes deleted (no other reader).
// DS reads/group-step: 6NJ -> 4NJ (A: vC only; B: Fcol-R, I-L, Fcol-L).
//  - Endpoint terms m=w (irR*dcRe) and m=0 (irL*dcLh) are group-uniform ->
//    added AFTER the DPP reduce; B loop is pure fma + boundary masks.
//  - SPILL SAFETY (R8/R10/R11): step body is a MACRO (textual inline, no
//    array-by-reference function params); all fS/iS indices are literals
//    from unrolled loops. Sentinel: WRITE_SIZE ~21KB (MB => revert to R17).
//  - Linear charts F''=exp2(F+ALPHA*width) (R16, absmax 0); phase-A load+fma
//    sharing between the span's two cells (R17). LG=8 only (R18/R19: LG=16
//    adaptation regressed; reverted).
//  - Select-after-compute masks garbage (0-init regs, clamped addresses).
//  - 8-lane DPP reduce; 4 blocks/CU; counting-sort + quartile-snake (R7).

#define NEGV   -1000000000.0f
#define NMAX   64
#define LDS_S  69
#define BLOCK  512
#define ALPHA  8.0f

#if __has_builtin(__builtin_amdgcn_exp2f)
#define EXP2F(x) __builtin_amdgcn_exp2f(x)
#else
#define EXP2F(x) __expf((x) * 0.6931471805599453f)
#endif
#if __has_builtin(__builtin_amdgcn_logf)
#define LOG2F(x) __builtin_amdgcn_logf(x)
#else
#define LOG2F(x) (__logf(x) * 1.4426950408889634f)
#endif
#define LOG2E 1.4426950408889634f
#define LN2   0.6931471805599453f

template<int CTRL>
__device__ __forceinline__ float dppf(float v) {
    return __int_as_float(__builtin_amdgcn_update_dpp(
        0, __float_as_int(v), CTRL, 0xF, 0xF, true));
}
__device__ __forceinline__ float grp8_sum(float s) {
    s += dppf<0xB1>(s);     // quad_perm xor 1
    s += dppf<0x4E>(s);     // quad_perm xor 2
    s += dppf<0x141>(s);    // row_half_mirror (joins quads)
    return s;
}

// ---- pre-kernel: counting sort by length (descending) + quartile-snake map ----
__global__ void order_kernel(const int* __restrict__ len_arr,
                             int* __restrict__ blk2item, int B)
{
    __shared__ int hist[33];
    __shared__ int base[33];
    const int tid = threadIdx.x;
    if (tid < 33) hist[tid] = 0;
    __syncthreads();
    int bin = 0;
    if (tid < B) {
        bin = 64 - len_arr[tid];          // 0 = longest
        atomicAdd(&hist[bin], 1);
    }
    __syncthreads();
    if (tid == 0) {
        int acc = 0;
        for (int i = 0; i < 33; ++i) { base[i] = acc; acc += hist[i]; }
    }
    __syncthreads();
    if (tid < B) {
        int rank = atomicAdd(&base[bin], 1);   // sorted-descending rank
        int j;
        if ((B & 255) == 0) {                   // snake across quartile stripes
            int q = rank >> 8, pos = rank & 255;
            j = (q & 1) ? ((q << 8) + 255 - pos) : ((q << 8) + pos);
        } else {
            j = rank;
        }
        blk2item[j] = tid;
    }
}

// Paired fused A+B step, NJ literal. Macro (not template fn) so fS/iS stay
// SROA-able scalars — no array-by-reference (R10 spill trap).
#define DMV_STEP(NJ)                                                          \
  {                                                                           \
    const int cd = nl - w;                                                    \
    if (gid < cd) {                                                           \
      const int h = gid, e = h + w;                                           \
      const int thh = th_s[h], the = th_s[e];                                 \
      const float trlR = EXP2F(trans_param[(thh * NMAX + the) * 2 + 1] * LOG2E + ALPHA); \
      const float trlL = EXP2F(trans_param[(the * NMAX + thh) * 2 + 0] * LOG2E + ALPHA); \
      const float gncR = goNCl[NMAX + h], gmR = goHMl[NMAX + h];              \
      const float gncL = goNCl[e],        gmL = goHMl[e];                     \
      const float dcR  = stNCl[NMAX + h], dcL = stNCl[e];                     \
      const float dcRe = stNCl[NMAX + e], dcLh = stNCl[h];                    \
      const int pC = e * LDS_S + h + 1;                                       \
      float sInt = 0.f, bndR = 0.f, bndL = 0.f;                               \
      _Pragma("unroll")                                                       \
      for (int j = 0; j < (NJ); ++j) {                                        \
        const int k = lg + 8 * j;                                             \
        if (j == (NJ) - 1) {                                                  \
          const int kc = (k < w) ? k : (w - 1);                               \
          const float vC = sF[pC + kc];                                       \
          const float vF = fS[j];                                             \
          const float tR = ((k == 0) ? gncR : vF * gmR) * ((k == w - 1) ? dcL : vC); \
          const float tL = ((k == w - 1) ? gncL : vC * gmL) * ((k == 0) ? dcR : vF); \
          bndR += (k < w) ? tR : 0.f;                                         \
          bndL += (k < w) ? tL : 0.f;                                         \
        } else if (j == 0) {                                                  \
          const float vC = sF[pC + k];                                        \
          const float vF = fS[0];                                             \
          bndR += ((k == 0) ? gncR : vF * gmR) * vC;                          \
          bndL += (vC * gmL) * ((k == 0) ? dcR : vF);                         \
        } else {                                                              \
          sInt = fmaf(fS[j], sF[pC + k], sInt);                               \
        }                                                                     \
      }                                                                       \
      const float aR = grp8_sum(fmaf(gmR, sInt, bndR));                       \
      const float aL = grp8_sum(fmaf(gmL, sInt, bndL));                       \
      const float irR = trlR * aR;                                            \
      const float irL = trlL * aL;                                            \
      if (lg == 1) sI[e * LDS_S + h] = irL;                                   \
      if ((NJ) < 8 && w == 8 * (NJ)) {                                        \
        if (lg == 0) iS[((NJ) < 8) ? (NJ) : 0] = irR;                         \
      } else {                                                                \
        if (lg == (w & 7)) iS[(NJ) - 1] = irR;                                \
      }                                                                       \
      const int pGR = h * LDS_S + e;                                          \
      const int pIL = e * LDS_S + h;                                          \
      const int pGL = h * LDS_S + h;                                          \
      float accR = 0.f, accL = 0.f;                                           \
      _Pragma("unroll")                                                       \
      for (int j = 0; j < (NJ); ++j) {                                        \
        const int m = lg + 8 * j;                                             \
        if (j == 0 || j == (NJ) - 1) {                                        \
          const bool ok = (m >= 1) && (m <= w - 1);                           \
          const int mc = ok ? m : 1;                                          \
          const float tR = iS[j] * sF[pGR + mc * LDS_S];                      \
          const float tL = sI[pIL + mc] * sF[pGL + mc * LDS_S];               \
          accR += ok ? tR : 0.f;                                              \
          accL += ok ? tL : 0.f;                                              \
        } else {                                                              \
          accR = fmaf(iS[j], sF[pGR + m * LDS_S], accR);                      \
          accL = fmaf(sI[pIL + m], sF[pGL + m * LDS_S], accL);                \
        }                                                                     \
      }                                                                       \
      const float bR = grp8_sum(accR) + irR * dcRe;                           \
      const float bL = grp8_sum(accL) + irL * dcLh;                           \
      const float fR = stHCl[NMAX + h] * bR;                                  \
      const float fL = stHCl[e] * bL;                                         \
      if (lg == 0) sF[h * LDS_S + e] = fR;                                    \
      if (lg == 1) sF[e * LDS_S + h] = fL;                                    \
      if ((NJ) < 8 && w == 8 * (NJ)) {                                        \
        if (lg == 0) fS[((NJ) < 8) ? (NJ) : 0] = fR;                          \
      } else {                                                                \
        if (lg == (w & 7)) fS[(NJ) - 1] = fR;                                 \
      }                                                                       \
    }                                                                         \
  }

__global__ __launch_bounds__(BLOCK, 8)
void dmv_inside_kernel(const int* __restrict__ tag,
                       const int* __restrict__ len_arr,
                       const float* __restrict__ root_param,
                       const float* __restrict__ trans_param,
                       const float* __restrict__ dec_param,
                       const int* __restrict__ blk2item,
                       float* __restrict__ out)
{
    __shared__ float sI[NMAX * LDS_S];     // I'' lower triangle only (left)
    __shared__ float sF[NMAX * LDS_S];     // F'' both triangles
    __shared__ float goNCl[2 * NMAX];      // linear params; [0]=L, [1]=R
    __shared__ float goHMl[2 * NMAX];      // exp2(go_hc - st_hc)
    __shared__ float stHCl[2 * NMAX];
    __shared__ float stNCl[2 * NMAX];      // width-0 "diagonal" of F'' (shift 0)
    __shared__ float root_l[NMAX];         // linear root
    __shared__ int   th_s[NMAX];

    const int b   = blk2item[blockIdx.x];  // balanced assignment
    const int tid = threadIdx.x;
    const int nl  = len_arr[b];            // 32..64; output depends only on [0,nl)

    if (tid < NMAX) {
        int t = tag[b * NMAX + tid];
        th_s[tid] = t;
        const float* d = dec_param + t * 8;   // [dir][val][dec], L=0 R=1
        goNCl[0 * NMAX + tid] = EXP2F(d[0] * LOG2E);
        stNCl[0 * NMAX + tid] = EXP2F(d[1] * LOG2E);
        goHMl[0 * NMAX + tid] = EXP2F((d[2] - d[3]) * LOG2E);
        stHCl[0 * NMAX + tid] = EXP2F(d[3] * LOG2E);
        goNCl[1 * NMAX + tid] = EXP2F(d[4] * LOG2E);
        stNCl[1 * NMAX + tid] = EXP2F(d[5] * LOG2E);
        goHMl[1 * NMAX + tid] = EXP2F((d[6] - d[7]) * LOG2E);
        stHCl[1 * NMAX + tid] = EXP2F(d[7] * LOG2E);
        root_l[tid]           = EXP2F(root_param[t] * LOG2E);
    }
    __syncthreads();

    const int gid = tid >> 3;      // 0..63 — fixed span head h=gid
    const int lg  = tid & 7;

    // per-lane register history for the group's right-side row:
    // fS[j] = F''[h][h+(lg+8j)], iS[j] = I''[h][h+(lg+8j)]; 0-init (masked).
    float fS[8], iS[8];
    #pragma unroll
    for (int i = 0; i < 8; ++i) { fS[i] = 0.f; iS[i] = 0.f; }

    for (int w = 1; w < nl; ++w) {
        switch ((w - 1) >> 3) {    // block-uniform dispatch, NJ=ceil(w/8)
        case 0: DMV_STEP(1); break;
        case 1: DMV_STEP(2); break;
        case 2: DMV_STEP(3); break;
        case 3: DMV_STEP(4); break;
        case 4: DMV_STEP(5); break;
        case 5: DMV_STEP(6); break;
        case 6: DMV_STEP(7); break;
        default: DMV_STEP(8); break;
        }
        __syncthreads();
    }

    // ---- final (linear): out = ln2*(log2( sum_i root_l*FL''*FR'' ) - ALPHA*last)
    if (tid < 64) {
        const int last = nl - 1;
        float fl0 = (tid == 0)    ? stNCl[0 * NMAX + 0]    : sF[tid * LDS_S + 0];
        float fre = (tid == last) ? stNCl[1 * NMAX + last] : sF[tid * LDS_S + last];
        float xx  = (tid < nl) ? (root_l[tid] * fl0 * fre) : 0.f;  // select kills NaN
        #pragma unroll
        for (int off = 1; off < 64; off <<= 1)
            xx += __shfl_xor(xx, off, 64);
        if (tid == 0) out[b] = (LOG2F(xx) - ALPHA * last) * LN2;
    }
}

extern "C" void kernel_launch(void* const* d_in, const int* in_sizes, int n_in,
                              void* d_out, int out_size, void* d_ws, size_t ws_size,
                              hipStream_t stream) {
    // setup_inputs order: id_array, tag_array, len_array, root_param, trans_param, dec_param
    const int*   tag   = (const int*)d_in[1];
    const int*   len_a = (const int*)d_in[2];
    const float* root  = (const float*)d_in[3];
    const float* trans = (const float*)d_in[4];
    const float* dec   = (const float*)d_in[5];
    float* outp = (float*)d_out;
    const int B = in_sizes[2];   // 1024

    int* blk2item = (int*)d_ws;  // B ints

    int sortThreads = (B < 1024) ? ((B + 63) & ~63) : 1024;
    if (sortThreads < 64) sortThreads = 64;
    order_kernel<<<1, sortThreads, 0, stream>>>(len_a, blk2item, B);
    dmv_inside_kernel<<<B, BLOCK, 0, stream>>>(tag, len_a, root, trans, dec,
                                               blk2item, outp);
}

// Round 21
// 65.826 us; speedup vs baseline: 1.0073x; 1.0073x over previous
//
#include <hip/hip_runtime.h>

// DMV inside — linear-domain sum-product, paired spans, A∥B DECOUPLED STEP.
// One block per batch item, 512 threads = 64 groups of 8; group g owns span
// (h=g, e=h+w), both direction cells. Base = R17 (51.2us best).
// NEW: phase B's only dependency on phase A was its endpoint term
// (d=w: irR*dcRe; d=0: irL*dcLh) consumed INSIDE B's loop -> the whole B
// chain serialized behind A's reduce. Restructure: B's lane-domain = OLD
// terms d=1..w-1 only (written at earlier widths, barrier-safe); A and B
// accumulate in ONE fused loop (all 6 streams' loads issue together, ILP);
// the two reduce pairs run in parallel; uniform endpoint terms attach
// post-reduce: fR = sth * fma(irR, dcRe, bR). Serial tail per step drops
// from (A-chain + reduce + B-chain + reduce) to (max chain + reduce + 3 ops).
//  - R20 erratum: register-history (fS/iS) added more VALU (slot-write
//    cndmasks) than it saved in DS — persistent-state family closed.
//  - Linear charts F''=exp2(F+ALPHA*width) (R16, absmax 0); phase-A load+fma
//    sharing between the span's two cells (R17). LG=8 only (R18/R19 lesson).
//  - B masks: top slot d<=w-1; j=0 slot fully valid for NJ>=2 (w>=9 => d<=8
//    <=w-1); NJ=1 masks per-lane (w=1: all masked, sum=0). Select-after-
//    compute discards garbage/NaN. No race: B reads only widths < w.
//  - 8-lane DPP reduce; 4 blocks/CU; counting-sort + quartile-snake (R7).
//  - Spill sentinel: WRITE_SIZE ~21KB (MB-scale => scratch, revert to R17).

#define NEGV   -1000000000.0f
#define NMAX   64
#define LDS_S  69
#define BLOCK  512
#define ALPHA  8.0f

#if __has_builtin(__builtin_amdgcn_exp2f)
#define EXP2F(x) __builtin_amdgcn_exp2f(x)
#else
#define EXP2F(x) __expf((x) * 0.6931471805599453f)
#endif
#if __has_builtin(__builtin_amdgcn_logf)
#define LOG2F(x) __builtin_amdgcn_logf(x)
#else
#define LOG2F(x) (__logf(x) * 1.4426950408889634f)
#endif
#define LOG2E 1.4426950408889634f
#define LN2   0.6931471805599453f

template<int CTRL>
__device__ __forceinline__ float dppf(float v) {
    return __int_as_float(__builtin_amdgcn_update_dpp(
        0, __float_as_int(v), CTRL, 0xF, 0xF, true));
}
__device__ __forceinline__ float grp8_sum(float s) {
    s += dppf<0xB1>(s);     // quad_perm xor 1
    s += dppf<0x4E>(s);     // quad_perm xor 2
    s += dppf<0x141>(s);    // row_half_mirror (joins quads)
    return s;
}

// ---- pre-kernel: counting sort by length (descending) + quartile-snake map ----
__global__ void order_kernel(const int* __restrict__ len_arr,
                             int* __restrict__ blk2item, int B)
{
    __shared__ int hist[33];
    __shared__ int base[33];
    const int tid = threadIdx.x;
    if (tid < 33) hist[tid] = 0;
    __syncthreads();
    int bin = 0;
    if (tid < B) {
        bin = 64 - len_arr[tid];          // 0 = longest
        atomicAdd(&hist[bin], 1);
    }
    __syncthreads();
    if (tid == 0) {
        int acc = 0;
        for (int i = 0; i < 33; ++i) { base[i] = acc; acc += hist[i]; }
    }
    __syncthreads();
    if (tid < B) {
        int rank = atomicAdd(&base[bin], 1);   // sorted-descending rank
        int j;
        if ((B & 255) == 0) {                   // snake across quartile stripes
            int q = rank >> 8, pos = rank & 255;
            j = (q & 1) ? ((q << 8) + 255 - pos) : ((q << 8) + pos);
        } else {
            j = rank;
        }
        blk2item[j] = tid;
    }
}

// Paired fused A+B step for span (h=gid, e=h+w). NJ = ceil(w/8), compile-time.
// All chart values LINEAR (trend-scaled). Params pre-exponentiated.
template<int NJ>
__device__ __forceinline__ void dmv_step(
    const int w, const int cd, const int gid, const int lg,
    float* __restrict__ sI, float* __restrict__ sF,
    const float* __restrict__ goNCl, const float* __restrict__ goHMl,
    const float* __restrict__ stHCl, const float* __restrict__ stNCl,
    const int* __restrict__ th_s, const float* __restrict__ trans_param)
{
    if (gid >= cd) return;
    const int h = gid, e = h + w;

    const int thh = th_s[h], the = th_s[e];
    const float trlR = EXP2F(trans_param[(thh * NMAX + the) * 2 + 1] * LOG2E + ALPHA);
    const float trlL = EXP2F(trans_param[(the * NMAX + thh) * 2 + 0] * LOG2E + ALPHA);
    const float gncR = goNCl[NMAX + h], gmR = goHMl[NMAX + h];
    const float gncL = goNCl[e],        gmL = goHMl[e];
    const float dcR  = stNCl[NMAX + h];   // FR[h][h] width-0 diag
    const float dcL  = stNCl[e];          // FL[e][e]
    const float dcRe = stNCl[NMAX + e];   // FR[e][e] (B right endpoint, d=w)
    const float dcLh = stNCl[h];          // FL[h][h] (B left endpoint, d=0)
    const float sthR = stHCl[NMAX + h];
    const float sthL = stHCl[e];

    // streams — A: vF = FR[h][h+k], vC = FL[e][h+1+k], k = 0..w-1
    //           B: I[h][h+d]*F[h+d][e] and I[e][h+d]*F[h+d][h], d = 1..w-1
    const int pF  = h * LDS_S + h;        // +k
    const int pC  = e * LDS_S + h + 1;    // +k
    const int pIU = h * LDS_S + h;        // +d   (upper I row)
    const int pFR = h * LDS_S + e;        // +d*LDS_S (F col e)
    const int pIL = e * LDS_S + h;        // +d   (lower I row)
    const int pFL = h * LDS_S + h;        // +d*LDS_S (F col h)

    float sInt = 0.f, bndR = 0.f, bndL = 0.f;   // A accumulators
    float accR = 0.f, accL = 0.f;               // B accumulators (old terms)
    #pragma unroll
    for (int j = 0; j < NJ; ++j) {
        const int k = lg + 8 * j;        // A domain
        const int d = k + 1;             // B domain
        // ---- phase A ----
        if (j == NJ - 1) {                    // top boundary: clamp+mask+selects
            const int kc = (k < w) ? k : (w - 1);
            float vF = sF[pF + kc];
            float vC = sF[pC + kc];
            float tR = ((k == 0) ? gncR : vF * gmR) * ((k == w - 1) ? dcL : vC);
            float tL = ((k == w - 1) ? gncL : vC * gmL) * ((k == 0) ? dcR : vF);
            bndR += (k < w) ? tR : 0.f;       // select AFTER compute: kills NaN
            bndL += (k < w) ? tL : 0.f;
        } else if (j == 0) {                  // bottom boundary (k<=7<=w-2 here)
            float vF = sF[pF + k];
            float vC = sF[pC + k];
            bndR += ((k == 0) ? gncR : vF * gmR) * vC;
            bndL += (vC * gmL) * ((k == 0) ? dcR : vF);
        } else {                              // interior: shared fma
            sInt = fmaf(sF[pF + k], sF[pC + k], sInt);
        }
        // ---- phase B (old widths only — independent of this step's A) ----
        if (j == NJ - 1) {                    // only slot needing a mask
            const bool ok = (d <= w - 1);
            const int  dc = ok ? d : 1;
            float tR = sI[pIU + dc] * sF[pFR + dc * LDS_S];
            float tL = sI[pIL + dc] * sF[pFL + dc * LDS_S];
            accR += ok ? tR : 0.f;
            accL += ok ? tL : 0.f;
        } else {                              // d <= 8(NJ-1) <= w-1: pure fma
            accR = fmaf(sI[pIU + d], sF[pFR + d * LDS_S], accR);
            accL = fmaf(sI[pIL + d], sF[pFL + d * LDS_S], accL);
        }
    }
    // parallel reduces; A's result feeds only a post-reduce uniform fma.
    const float aR = grp8_sum(fmaf(gmR, sInt, bndR));
    const float aL = grp8_sum(fmaf(gmL, sInt, bndL));
    const float bR = grp8_sum(accR);
    const float bL = grp8_sum(accL);
    const float irR = trlR * aR;              // group-uniform after DPP
    const float irL = trlL * aL;
    const float fR = sthR * fmaf(irR, dcRe, bR);
    const float fL = sthL * fmaf(irL, dcLh, bL);
    if (lg == 0) { sI[h * LDS_S + e] = irR; sF[h * LDS_S + e] = fR; }
    if (lg == 1) { sI[e * LDS_S + h] = irL; sF[e * LDS_S + h] = fL; }
}

__global__ __launch_bounds__(BLOCK, 8)
void dmv_inside_kernel(const int* __restrict__ tag,
                       const int* __restrict__ len_arr,
                       const float* __restrict__ root_param,
                       const float* __restrict__ trans_param,
                       const float* __restrict__ dec_param,
                       const int* __restrict__ blk2item,
                       float* __restrict__ out)
{
    __shared__ float sI[NMAX * LDS_S];     // I'' (linear, trend-scaled)
    __shared__ float sF[NMAX * LDS_S];     // F'' (linear, trend-scaled)
    __shared__ float goNCl[2 * NMAX];      // linear params; [0]=L, [1]=R
    __shared__ float goHMl[2 * NMAX];      // exp2(go_hc - st_hc)
    __shared__ float stHCl[2 * NMAX];
    __shared__ float stNCl[2 * NMAX];      // width-0 "diagonal" of F'' (shift 0)
    __shared__ float root_l[NMAX];         // linear root
    __shared__ int   th_s[NMAX];

    const int b   = blk2item[blockIdx.x];  // balanced assignment
    const int tid = threadIdx.x;
    const int nl  = len_arr[b];            // 32..64; output depends only on [0,nl)

    if (tid < NMAX) {
        int t = tag[b * NMAX + tid];
        th_s[tid] = t;
        const float* d = dec_param + t * 8;   // [dir][val][dec], L=0 R=1
        goNCl[0 * NMAX + tid] = EXP2F(d[0] * LOG2E);
        stNCl[0 * NMAX + tid] = EXP2F(d[1] * LOG2E);
        goHMl[0 * NMAX + tid] = EXP2F((d[2] - d[3]) * LOG2E);
        stHCl[0 * NMAX + tid] = EXP2F(d[3] * LOG2E);
        goNCl[1 * NMAX + tid] = EXP2F(d[4] * LOG2E);
        stNCl[1 * NMAX + tid] = EXP2F(d[5] * LOG2E);
        goHMl[1 * NMAX + tid] = EXP2F((d[6] - d[7]) * LOG2E);
        stHCl[1 * NMAX + tid] = EXP2F(d[7] * LOG2E);
        root_l[tid]           = EXP2F(root_param[t] * LOG2E);
    }
    __syncthreads();

    const int gid = tid >> 3;      // 0..63 — one span (two cells) per group
    const int lg  = tid & 7;

    for (int w = 1; w < nl; ++w) {
        const int cd = nl - w;     // spans this step (<= 63 <= 64 groups)
        switch ((w - 1) >> 3) {    // block-uniform dispatch, NJ=ceil(w/8)
        case 0: dmv_step<1>(w, cd, gid, lg, sI, sF, goNCl, goHMl, stHCl, stNCl, th_s, trans_param); break;
        case 1: dmv_step<2>(w, cd, gid, lg, sI, sF, goNCl, goHMl, stHCl, stNCl, th_s, trans_param); break;
        case 2: dmv_step<3>(w, cd, gid, lg, sI, sF, goNCl, goHMl, stHCl, stNCl, th_s, trans_param); break;
        case 3: dmv_step<4>(w, cd, gid, lg, sI, sF, goNCl, goHMl, stHCl, stNCl, th_s, trans_param); break;
        case 4: dmv_step<5>(w, cd, gid, lg, sI, sF, goNCl, goHMl, stHCl, stNCl, th_s, trans_param); break;
        case 5: dmv_step<6>(w, cd, gid, lg, sI, sF, goNCl, goHMl, stHCl, stNCl, th_s, trans_param); break;
        case 6: dmv_step<7>(w, cd, gid, lg, sI, sF, goNCl, goHMl, stHCl, stNCl, th_s, trans_param); break;
        default: dmv_step<8>(w, cd, gid, lg, sI, sF, goNCl, goHMl, stHCl, stNCl, th_s, trans_param); break;
        }
        __syncthreads();
    }

    // ---- final (linear): out = ln2*(log2( sum_i root_l*FL''*FR'' ) - ALPHA*last)
    if (tid < 64) {
        const int last = nl - 1;
        float fl0 = (tid == 0)    ? stNCl[0 * NMAX + 0]    : sF[tid * LDS_S + 0];
        float fre = (tid == last) ? stNCl[1 * NMAX + last] : sF[tid * LDS_S + last];
        float xx  = (tid < nl) ? (root_l[tid] * fl0 * fre) : 0.f;  // select kills NaN
        #pragma unroll
        for (int off = 1; off < 64; off <<= 1)
            xx += __shfl_xor(xx, off, 64);
        if (tid == 0) out[b] = (LOG2F(xx) - ALPHA * last) * LN2;
    }
}

extern "C" void kernel_launch(void* const* d_in, const int* in_sizes, int n_in,
                              void* d_out, int out_size, void* d_ws, size_t ws_size,
                              hipStream_t stream) {
    // setup_inputs order: id_array, tag_array, len_array, root_param, trans_param, dec_param
    const int*   tag   = (const int*)d_in[1];
    const int*   len_a = (const int*)d_in[2];
    const float* root  = (const float*)d_in[3];
    const float* trans = (const float*)d_in[4];
    const float* dec   = (const float*)d_in[5];
    float* outp = (float*)d_out;
    const int B = in_sizes[2];   // 1024

    int* blk2item = (int*)d_ws;  // B ints

    int sortThreads = (B < 1024) ? ((B + 63) & ~63) : 1024;
    if (sortThreads < 64) sortThreads = 64;
    order_kernel<<<1, sortThreads, 0, stream>>>(len_a, blk2item, B);
    dmv_inside_kernel<<<B, BLOCK, 0, stream>>>(tag, len_a, root, trans, dec,
                                               blk2item, outp);
}

// Round 22
// 55.095 us; speedup vs baseline: 1.2035x; 1.1948x over previous
//
#include <hip/hip_runtime.h>

// DMV inside — linear-domain sum-product, PAIRED SPANS. One block per batch
// item, 512 threads = 64 groups of 8; group g owns span (h=g, e=h+w) and
// computes BOTH direction cells.  [MEASURED OPTIMUM — R17, 51.2us steady.
// Reverted here after four independent step-latency attacks all regressed:
// LG=16 adaptation (R18 63 / R19 52.8), register history (R20 64.2),
// A||B fused loop (R21 61.4). Latency-bound plateau: 63 barrier steps x
// (LDS latency + DPP reduce + barrier drain), 4-way block interleave.]
//  - Linear charts F''=exp2(F+ALPHA*width) (R16, absmax 0.0): sum-product
//    with 1 fma/interior slot; exp2/log2 out of the inner loops entirely.
//  - PAIRING: both cells' phase A read the SAME segments FR[h][h..e-1],
//    FL[e][h+1..e]; interior term right = gmR*(vF*vC), left = gmL*(vF*vC)
//    -> ONE shared fma/slot, gm folded post-loop: fma(gm*, sInt, bnd*).
//  - Boundary selects only in 2 slots (j==0: k=0; j==NJ-1: k=w-1 + tail
//    mask). Select-AFTER-compute discards garbage/NaN. Width-w I/F values
//    consumed via registers irR/irL within the step; no write race.
//  - Ascending addressing, compile-time per-j offsets, single template body,
//    scalars only (spill-safe; sentinel: WRITE_SIZE ~21KB).
//  - 8-lane DPP reduce (quad_perm xor1/xor2 + row_half_mirror). 4 blocks/CU,
//    32 waves/CU; counting-sort + quartile-snake load balance (R7).

#define NEGV   -1000000000.0f
#define NMAX   64
#define LDS_S  69
#define BLOCK  512
#define ALPHA  8.0f

#if __has_builtin(__builtin_amdgcn_exp2f)
#define EXP2F(x) __builtin_amdgcn_exp2f(x)
#else
#define EXP2F(x) __expf((x) * 0.6931471805599453f)
#endif
#if __has_builtin(__builtin_amdgcn_logf)
#define LOG2F(x) __builtin_amdgcn_logf(x)
#else
#define LOG2F(x) (__logf(x) * 1.4426950408889634f)
#endif
#define LOG2E 1.4426950408889634f
#define LN2   0.6931471805599453f

template<int CTRL>
__device__ __forceinline__ float dppf(float v) {
    return __int_as_float(__builtin_amdgcn_update_dpp(
        0, __float_as_int(v), CTRL, 0xF, 0xF, true));
}
__device__ __forceinline__ float grp8_sum(float s) {
    s += dppf<0xB1>(s);     // quad_perm xor 1
    s += dppf<0x4E>(s);     // quad_perm xor 2
    s += dppf<0x141>(s);    // row_half_mirror (joins quads in 8-lane group)
    return s;
}

// ---- pre-kernel: counting sort by length (descending) + quartile-snake map ----
__global__ void order_kernel(const int* __restrict__ len_arr,
                             int* __restrict__ blk2item, int B)
{
    __shared__ int hist[33];
    __shared__ int base[33];
    const int tid = threadIdx.x;
    if (tid < 33) hist[tid] = 0;
    __syncthreads();
    int bin = 0;
    if (tid < B) {
        bin = 64 - len_arr[tid];          // 0 = longest
        atomicAdd(&hist[bin], 1);
    }
    __syncthreads();
    if (tid == 0) {
        int acc = 0;
        for (int i = 0; i < 33; ++i) { base[i] = acc; acc += hist[i]; }
    }
    __syncthreads();
    if (tid < B) {
        int rank = atomicAdd(&base[bin], 1);   // sorted-descending rank
        int j;
        if ((B & 255) == 0) {                   // snake across quartile stripes
            int q = rank >> 8, pos = rank & 255;
            j = (q & 1) ? ((q << 8) + 255 - pos) : ((q << 8) + pos);
        } else {
            j = rank;
        }
        blk2item[j] = tid;
    }
}

// Paired fused A+B step for span (h=gid, e=h+w). NJ = ceil(w/8), compile-time.
// All chart values LINEAR (trend-scaled). Params pre-exponentiated.
template<int NJ>
__device__ __forceinline__ void dmv_step(
    const int w, const int cd, const int gid, const int lg,
    float* __restrict__ sI, float* __restrict__ sF,
    const float* __restrict__ goNCl, const float* __restrict__ goHMl,
    const float* __restrict__ stHCl, const float* __restrict__ stNCl,
    const int* __restrict__ th_s, const float* __restrict__ trans_param)
{
    if (gid >= cd) return;
    const int h = gid, e = h + w;

    const int thh = th_s[h], the = th_s[e];
    const float trlR = EXP2F(trans_param[(thh * NMAX + the) * 2 + 1] * LOG2E + ALPHA);
    const float trlL = EXP2F(trans_param[(the * NMAX + thh) * 2 + 0] * LOG2E + ALPHA);
    const float gncR = goNCl[NMAX + h], gmR = goHMl[NMAX + h];
    const float gncL = goNCl[e],        gmL = goHMl[e];
    const float dcR  = stNCl[NMAX + h];   // FR[h][h] width-0 diag
    const float dcL  = stNCl[e];          // FL[e][e]
    const float dcRe = stNCl[NMAX + e];   // FR[e][e] (B right endpoint)
    const float dcLh = stNCl[h];          // FL[h][h] (B left endpoint)

    // ---- phase A (shared streams): vF = FR[h][h+k], vC = FL[e][h+1+k] ----
    const int pF = h * LDS_S + h;        // +k
    const int pC = e * LDS_S + h + 1;    // +k
    float sInt = 0.f, bndR = 0.f, bndL = 0.f;
    #pragma unroll
    for (int j = 0; j < NJ; ++j) {
        const int k = lg + 8 * j;
        if (j == NJ - 1) {                    // top boundary: clamp+mask+selects
            const int kc = (k < w) ? k : (w - 1);
            float vF = sF[pF + kc];
            float vC = sF[pC + kc];
            float tR = ((k == 0) ? gncR : vF * gmR) * ((k == w - 1) ? dcL : vC);
            float tL = ((k == w - 1) ? gncL : vC * gmL) * ((k == 0) ? dcR : vF);
            bndR += (k < w) ? tR : 0.f;       // select AFTER compute: kills NaN
            bndL += (k < w) ? tL : 0.f;
        } else if (j == 0) {                  // bottom boundary (k<=7<=w-2 here)
            float vF = sF[pF + k];
            float vC = sF[pC + k];
            bndR += ((k == 0) ? gncR : vF * gmR) * vC;
            bndL += (vC * gmL) * ((k == 0) ? dcR : vF);
        } else {                              // interior: shared fma
            sInt = fmaf(sF[pF + k], sF[pC + k], sInt);
        }
    }
    const float aR = grp8_sum(fmaf(gmR, sInt, bndR));
    const float aL = grp8_sum(fmaf(gmL, sInt, bndL));
    const float irR = trlR * aR;              // group-uniform after DPP
    const float irL = trlL * aL;
    if (lg == 0) sI[h * LDS_S + e] = irR;
    if (lg == 1) sI[e * LDS_S + h] = irL;

    // ---- phase B (independent streams):
    // right: sum_k I_R[h][h+1+k] * F[h+1+k][e], k=0..w-1 (k=w-1 -> irR*dcRe)
    // left:  sum_m I_L[e][h+m]   * F[h+m][h],   m=0..w-1 (m=0   -> irL*dcLh)
    const int pIR = h * LDS_S + h + 1;    // +k
    const int pGR = (h + 1) * LDS_S + e;  // +k*LDS_S
    const int pIL = e * LDS_S + h;        // +m
    const int pGL = h * LDS_S + h;        // +m*LDS_S
    float accR = 0.f, accL = 0.f;
    #pragma unroll
    for (int j = 0; j < NJ; ++j) {
        const int k = lg + 8 * j;
        if (j == NJ - 1) {
            const int kc = (k < w) ? k : (w - 1);
            float i1 = sI[pIR + kc];
            float f1 = sF[pGR + kc * LDS_S];
            float i2 = sI[pIL + kc];
            float f2 = sF[pGL + kc * LDS_S];
            float tR = ((k == w - 1) ? irR : i1) * ((k == w - 1) ? dcRe : f1);
            float tL = ((k == 0) ? irL : i2) * ((k == 0) ? dcLh : f2);
            accR += (k < w) ? tR : 0.f;
            accL += (k < w) ? tL : 0.f;
        } else if (j == 0) {                  // k<=7<w-1: right has no special
            float i1 = sI[pIR + k];
            float f1 = sF[pGR + k * LDS_S];
            float i2 = sI[pIL + k];
            float f2 = sF[pGL + k * LDS_S];
            accR = fmaf(i1, f1, accR);
            accL += ((k == 0) ? irL : i2) * ((k == 0) ? dcLh : f2);
        } else {
            accR = fmaf(sI[pIR + k], sF[pGR + k * LDS_S], accR);
            accL = fmaf(sI[pIL + k], sF[pGL + k * LDS_S], accL);
        }
    }
    const float bR = grp8_sum(accR);
    const float bL = grp8_sum(accL);
    if (lg == 0) sF[h * LDS_S + e] = stHCl[NMAX + h] * bR;
    if (lg == 1) sF[e * LDS_S + h] = stHCl[e] * bL;
}

__global__ __launch_bounds__(BLOCK, 8)
void dmv_inside_kernel(const int* __restrict__ tag,
                       const int* __restrict__ len_arr,
                       const float* __restrict__ root_param,
                       const float* __restrict__ trans_param,
                       const float* __restrict__ dec_param,
                       const int* __restrict__ blk2item,
                       float* __restrict__ out)
{
    __shared__ float sI[NMAX * LDS_S];     // I'' (linear, trend-scaled)
    __shared__ float sF[NMAX * LDS_S];     // F'' (linear, trend-scaled)
    __shared__ float goNCl[2 * NMAX];      // linear params; [0]=L, [1]=R
    __shared__ float goHMl[2 * NMAX];      // exp2(go_hc - st_hc)
    __shared__ float stHCl[2 * NMAX];
    __shared__ float stNCl[2 * NMAX];      // width-0 "diagonal" of F'' (shift 0)
    __shared__ float root_l[NMAX];         // linear root
    __shared__ int   th_s[NMAX];

    const int b   = blk2item[blockIdx.x];  // balanced assignment
    const int tid = threadIdx.x;
    const int nl  = len_arr[b];            // 32..64; output depends only on [0,nl)

    if (tid < NMAX) {
        int t = tag[b * NMAX + tid];
        th_s[tid] = t;
        const float* d = dec_param + t * 8;   // [dir][val][dec], L=0 R=1
        goNCl[0 * NMAX + tid] = EXP2F(d[0] * LOG2E);
        stNCl[0 * NMAX + tid] = EXP2F(d[1] * LOG2E);
        goHMl[0 * NMAX + tid] = EXP2F((d[2] - d[3]) * LOG2E);
        stHCl[0 * NMAX + tid] = EXP2F(d[3] * LOG2E);
        goNCl[1 * NMAX + tid] = EXP2F(d[4] * LOG2E);
        stNCl[1 * NMAX + tid] = EXP2F(d[5] * LOG2E);
        goHMl[1 * NMAX + tid] = EXP2F((d[6] - d[7]) * LOG2E);
        stHCl[1 * NMAX + tid] = EXP2F(d[7] * LOG2E);
        root_l[tid]           = EXP2F(root_param[t] * LOG2E);
    }
    __syncthreads();

    const int gid = tid >> 3;      // 0..63 — one span (two cells) per group
    const int lg  = tid & 7;

    for (int w = 1; w < nl; ++w) {
        const int cd = nl - w;     // spans this step (<= 63 <= 64 groups)
        switch ((w - 1) >> 3) {    // block-uniform dispatch, NJ=ceil(w/8)
        case 0: dmv_step<1>(w, cd, gid, lg, sI, sF, goNCl, goHMl, stHCl, stNCl, th_s, trans_param); break;
        case 1: dmv_step<2>(w, cd, gid, lg, sI, sF, goNCl, goHMl, stHCl, stNCl, th_s, trans_param); break;
        case 2: dmv_step<3>(w, cd, gid, lg, sI, sF, goNCl, goHMl, stHCl, stNCl, th_s, trans_param); break;
        case 3: dmv_step<4>(w, cd, gid, lg, sI, sF, goNCl, goHMl, stHCl, stNCl, th_s, trans_param); break;
        case 4: dmv_step<5>(w, cd, gid, lg, sI, sF, goNCl, goHMl, stHCl, stNCl, th_s, trans_param); break;
        case 5: dmv_step<6>(w, cd, gid, lg, sI, sF, goNCl, goHMl, stHCl, stNCl, th_s, trans_param); break;
        case 6: dmv_step<7>(w, cd, gid, lg, sI, sF, goNCl, goHMl, stHCl, stNCl, th_s, trans_param); break;
        default: dmv_step<8>(w, cd, gid, lg, sI, sF, goNCl, goHMl, stHCl, stNCl, th_s, trans_param); break;
        }
        __syncthreads();
    }

    // ---- final (linear): out = ln2*(log2( sum_i root_l*FL''*FR'' ) - ALPHA*last)
    if (tid < 64) {
        const int last = nl - 1;
        float fl0 = (tid == 0)    ? stNCl[0 * NMAX + 0]    : sF[tid * LDS_S + 0];
        float fre = (tid == last) ? stNCl[1 * NMAX + last] : sF[tid * LDS_S + last];
        float xx  = (tid < nl) ? (root_l[tid] * fl0 * fre) : 0.f;  // select kills NaN
        #pragma unroll
        for (int off = 1; off < 64; off <<= 1)
            xx += __shfl_xor(xx, off, 64);
        if (tid == 0) out[b] = (LOG2F(xx) - ALPHA * last) * LN2;
    }
}

extern "C" void kernel_launch(void* const* d_in, const int* in_sizes, int n_in,
                              void* d_out, int out_size, void* d_ws, size_t ws_size,
                              hipStream_t stream) {
    // setup_inputs order: id_array, tag_array, len_array, root_param, trans_param, dec_param
    const int*   tag   = (const int*)d_in[1];
    const int*   len_a = (const int*)d_in[2];
    const float* root  = (const float*)d_in[3];
    const float* trans = (const float*)d_in[4];
    const float* dec   = (const float*)d_in[5];
    float* outp = (float*)d_out;
    const int B = in_sizes[2];   // 1024

    int* blk2item = (int*)d_ws;  // B ints

    int sortThreads = (B < 1024) ? ((B + 63) & ~63) : 1024;
    if (sortThreads < 64) sortThreads = 64;
    order_kernel<<<1, sortThreads, 0, stream>>>(len_a, blk2item, B);
    dmv_inside_kernel<<<B, BLOCK, 0, stream>>>(tag, len_a, root, trans, dec,
                                               blk2item, outp);
}